// Round 6
// baseline (2693.893 us; speedup 1.0000x reference)
//
#include <hip/hip_runtime.h>
#include <hip/hip_bf16.h>
#include <stdint.h>

typedef __bf16 bf16x8 __attribute__((ext_vector_type(8)));
typedef float  f32x16 __attribute__((ext_vector_type(16)));

#define FMPX 19
#define NPOS 361
#define CCH  512
#define NB   16
#define NCLS 20
#define CONF_T 0.001f
#define NMS_TH 0.6f
#define BSCALE (32.0f/608.0f)

#define SC_OFF   (NB*NPOS*4)
#define CLS_OFF  (SC_OFF + NB*NPOS)
#define KEEP_OFF (CLS_OFF + NB*NPOS)

#define GSTR  3528                     // 441 rows * 8 ci elems
#define PLANE ((size_t)3612672)        // 16 b * 64 g * 3528
#define XBUF  24576                    // 3pl * 2kh * 4096B (252 rows*16B padded to 4096)
#define SMEMB 55296                    // max(2*XBUF=49152, Lf 4*96*36*4=55296)

__device__ __forceinline__ void gl_lds16(const void* g, void* l) {
  __builtin_amdgcn_global_load_lds(
      (const __attribute__((address_space(1))) unsigned int*)g,
      (__attribute__((address_space(3))) unsigned int*)l, 16, 0, 0);
}
#define MFMA32(A,B,C) __builtin_amdgcn_mfma_f32_32x32x16_bf16(A,B,C,0,0,0)
#define SBAR() __builtin_amdgcn_sched_barrier(0)
#define PRIO1 __builtin_amdgcn_s_setprio(1)
#define PRIO0 __builtin_amdgcn_s_setprio(0)

// tap byte offsets in padded-row LDS (goffs*16)
#define GOF0 (-352)
#define GOF1 (-336)
#define GOF2 (-320)
#define GOF3 (-16)
#define GOF4 (0)
#define GOF5 (16)
#define GOF6 (320)
#define GOF7 (336)
#define GOF8 (352)
#define GO16(T) (GOF##T)

// ---------------- split x: f32 NCHW -> 3 bf16 planes [pl][b][g][row441][8ci]
__global__ void split_x_k(const float* __restrict__ x, __bf16* __restrict__ Xd) {
  __shared__ float sx[8][368];
  int g = blockIdx.x, b = blockIdx.y;
  int tid = threadIdx.x;
  for (int i = tid; i < 8*361; i += 256) {
    int ci = i / 361, p = i - ci*361;
    sx[ci][p] = x[((size_t)b*CCH + g*8 + ci)*NPOS + p];
  }
  __syncthreads();
  for (int row = tid; row < 441; row += 256) {
    int y = row/21, xx = row - y*21;
    bf16x8 oh = {}, om = {}, ol = {};
    if (y >= 1 && y <= 19 && xx >= 1 && xx <= 19) {
      int p = (y-1)*19 + xx - 1;
#pragma unroll
      for (int j = 0; j < 8; ++j) {
        float v = sx[j][p];
        __bf16 hh = (__bf16)v; float r1 = v - (float)hh;
        __bf16 mm = (__bf16)r1;
        oh[j] = hh; om[j] = mm; ol[j] = (__bf16)(r1 - (float)mm);
      }
    }
    size_t o = (((size_t)b)*64 + g)*GSTR + (size_t)row*8;
    *(bf16x8*)(Xd + o)           = oh;
    *(bf16x8*)(Xd + PLANE + o)   = om;
    *(bf16x8*)(Xd + 2*PLANE + o) = ol;
  }
}

// ---------------- weight repack+split: w[co][ci][3][3] f32 ->
//  Wg [slice16][pl3][tap9][chunk32][kh2][co32][8ci] bf16
__global__ void repack_k(const float* __restrict__ w, __bf16* __restrict__ Wg) {
  __shared__ float sw[32][145];
  int slice = blockIdx.x, chunk = blockIdx.y;
  int tid = threadIdx.x;
  for (int i = tid; i < 32*144; i += 256) {
    int cl = i / 144, r = i - cl*144;
    sw[cl][r] = w[((size_t)slice*32 + cl)*4608 + chunk*144 + r];
  }
  __syncthreads();
  for (int u = tid; u < 1728; u += 256) {
    int co = u & 31, kh = (u >> 5) & 1, pt = u >> 6;
    int tap = pt % 9, pl = pt / 9;
    bf16x8 o;
#pragma unroll
    for (int j = 0; j < 8; ++j) {
      float v = sw[co][(kh*8 + j)*9 + tap];
      __bf16 hh = (__bf16)v; float r1 = v - (float)hh;
      __bf16 mm = (__bf16)r1;
      o[j] = pl == 0 ? hh : (pl == 1 ? mm : (__bf16)(r1 - (float)mm));
    }
    *(bf16x8*)(Wg + ((((size_t)slice*3 + pl)*9 + tap)*32 + chunk)*512 + kh*256 + co*8) = o;
  }
}

// B fragment from global (perfectly coalesced 1KB/wave)
#define LW(PL, T, C) (*(const bf16x8*)(gWb + (size_t)(PL)*147456 + (T)*16384 + (C)*512))

#define RDA6(SP, PL, T) do { \
  SP##0 = *(const bf16x8*)(Xc + (PL)*8192 + kh4096 + aoff0 + GO16(T)); \
  SP##1 = *(const bf16x8*)(Xc + (PL)*8192 + kh4096 + aoff1 + GO16(T)); \
  SP##2 = *(const bf16x8*)(Xc + (PL)*8192 + kh4096 + aoff2 + GO16(T)); \
  SP##3 = *(const bf16x8*)(Xc + (PL)*8192 + kh4096 + aoff3 + GO16(T)); \
  SP##4 = *(const bf16x8*)(Xc + (PL)*8192 + kh4096 + aoff4 + GO16(T)); \
  SP##5 = *(const bf16x8*)(Xc + (PL)*8192 + kh4096 + aoff5 + GO16(T)); } while (0)

#define CL0(SP, BHX, BMX, BLX) do { PRIO1; \
  acc0 = MFMA32(SP##0, BHX, acc0); acc1 = MFMA32(SP##1, BHX, acc1); \
  acc2 = MFMA32(SP##2, BHX, acc2); acc3 = MFMA32(SP##3, BHX, acc3); \
  acc4 = MFMA32(SP##4, BHX, acc4); acc5 = MFMA32(SP##5, BHX, acc5); \
  acc0 = MFMA32(SP##0, BMX, acc0); acc1 = MFMA32(SP##1, BMX, acc1); \
  acc2 = MFMA32(SP##2, BMX, acc2); acc3 = MFMA32(SP##3, BMX, acc3); \
  acc4 = MFMA32(SP##4, BMX, acc4); acc5 = MFMA32(SP##5, BMX, acc5); \
  acc0 = MFMA32(SP##0, BLX, acc0); acc1 = MFMA32(SP##1, BLX, acc1); \
  acc2 = MFMA32(SP##2, BLX, acc2); acc3 = MFMA32(SP##3, BLX, acc3); \
  acc4 = MFMA32(SP##4, BLX, acc4); acc5 = MFMA32(SP##5, BLX, acc5); \
  PRIO0; } while (0)

#define CL1A(SP, BHX, BMX) do { PRIO1; \
  acc0 = MFMA32(SP##0, BHX, acc0); acc1 = MFMA32(SP##1, BHX, acc1); \
  acc2 = MFMA32(SP##2, BHX, acc2); acc3 = MFMA32(SP##3, BHX, acc3); \
  acc4 = MFMA32(SP##4, BHX, acc4); acc5 = MFMA32(SP##5, BHX, acc5); \
  acc0 = MFMA32(SP##0, BMX, acc0); acc1 = MFMA32(SP##1, BMX, acc1); \
  acc2 = MFMA32(SP##2, BMX, acc2); acc3 = MFMA32(SP##3, BMX, acc3); \
  acc4 = MFMA32(SP##4, BMX, acc4); acc5 = MFMA32(SP##5, BMX, acc5); \
  PRIO0; } while (0)

#define CL1B(SP, BHX) do { PRIO1; \
  acc0 = MFMA32(SP##0, BHX, acc0); acc1 = MFMA32(SP##1, BHX, acc1); \
  acc2 = MFMA32(SP##2, BHX, acc2); acc3 = MFMA32(SP##3, BHX, acc3); \
  acc4 = MFMA32(SP##4, BHX, acc4); acc5 = MFMA32(SP##5, BHX, acc5); \
  PRIO0; } while (0)

#define STO(A, MTL) do { _Pragma("unroll") \
  for (int r = 0; r < 16; ++r) { \
    Lf[wq*3456 + ((MTL)*32 + 4*kh + (r & 3) + 8*(r >> 2))*36 + col] = (A)[r]; } } while (0)

// ---------------- 3x3 conv: grid 512 (b,slice,h), 256 thr = 4 waves (s,tg)
// wave: 6 m-tiles x 32 co; A from LDS (double-buffered), B from global (L2)
__global__ __launch_bounds__(256, 2) void conv3x3_mfma(
    const __bf16* __restrict__ Xs, const __bf16* __restrict__ Wg,
    const float* __restrict__ bias, __bf16* __restrict__ Xd)
{
  __shared__ __attribute__((aligned(16))) char smem[SMEMB];
  const int tid = threadIdx.x;
  const int bid = blockIdx.x;
  const int b = bid & 15, slice = (bid >> 4) & 15, h = bid >> 8;
  const int lane = tid & 63;
  const int wq = __builtin_amdgcn_readfirstlane(tid >> 6);
  const int s = wq & 1, tg = wq >> 1;
  const int col = lane & 31, kh = lane >> 5;
  const int kh4096 = kh*4096;
  const int PB = h*190, CNT = h ? 171 : 190;
  const int PEND = PB + CNT - 1;

  // A LDS byte offsets per m-tile (local padded row * 16)
  int aoff0, aoff1, aoff2, aoff3, aoff4, aoff5;
  {
    int ao[6];
#pragma unroll
    for (int mt = 0; mt < 6; ++mt) {
      int p = PB + mt*32 + col; if (p > PEND) p = PEND;
      int pp = p + 2*(p/19) + 22;
      ao[mt] = (pp - h*210)*16;
    }
    aoff0 = ao[0]; aoff1 = ao[1]; aoff2 = ao[2];
    aoff3 = ao[3]; aoff4 = ao[4]; aoff5 = ao[5];
  }
  const __bf16* gWb = Wg + (size_t)slice*442368 + (size_t)lane*8;
  const int clampU = h ? 230 : 251;

  auto stageX = [&](int c1, int buf) {
#pragma unroll
    for (int r = 0; r < 6; ++r) {
      const int i = wq*6 + r;
      const int pl = i >> 3, khs = (i >> 2) & 1, j = i & 3;
      int u = j*64 + lane; if (u > clampU) u = clampU;
      gl_lds16(Xs + ((size_t)pl*16 + b)*64*GSTR + (size_t)(2*c1 + khs)*GSTR
                   + (size_t)(h*210 + u)*8,
               smem + buf*XBUF + (pl*2 + khs)*4096 + j*1024);
    }
  };

  f32x16 acc0 = {}, acc1 = {}, acc2 = {}, acc3 = {}, acc4 = {}, acc5 = {};

  stageX(0, 0);
  __syncthreads();

  for (int c = 0; c < 32; ++c) {
    const char* Xc = smem + (c & 1)*XBUF;
    if (s == 0) {
      bf16x8 Aa0, Aa1, Aa2, Aa3, Aa4, Aa5, Ab0, Ab1, Ab2, Ab3, Ab4, Ab5;
      bf16x8 BH[5], BM[5], BL[5];
      if (tg == 0) {   // taps 0..3, products Ah*(Bh,Bm,Bl)
        RDA6(Aa, 0, 0);
#pragma unroll
        for (int k2 = 0; k2 < 4; ++k2) {
          BH[k2] = LW(0, k2, c); BM[k2] = LW(1, k2, c); BL[k2] = LW(2, k2, c);
        }
        if (c < 31) stageX(c + 1, (c + 1) & 1);
        SBAR();
        RDA6(Ab, 0, 1); SBAR(); CL0(Aa, BH[0], BM[0], BL[0]); SBAR();
        RDA6(Aa, 0, 2); SBAR(); CL0(Ab, BH[1], BM[1], BL[1]); SBAR();
        RDA6(Ab, 0, 3); SBAR(); CL0(Aa, BH[2], BM[2], BL[2]); SBAR();
        CL0(Ab, BH[3], BM[3], BL[3]);
      } else {         // taps 4..8
        RDA6(Aa, 0, 4);
#pragma unroll
        for (int k2 = 0; k2 < 5; ++k2) {
          BH[k2] = LW(0, 4 + k2, c); BM[k2] = LW(1, 4 + k2, c); BL[k2] = LW(2, 4 + k2, c);
        }
        if (c < 31) stageX(c + 1, (c + 1) & 1);
        SBAR();
        RDA6(Ab, 0, 5); SBAR(); CL0(Aa, BH[0], BM[0], BL[0]); SBAR();
        RDA6(Aa, 0, 6); SBAR(); CL0(Ab, BH[1], BM[1], BL[1]); SBAR();
        RDA6(Ab, 0, 7); SBAR(); CL0(Aa, BH[2], BM[2], BL[2]); SBAR();
        RDA6(Aa, 0, 8); SBAR(); CL0(Ab, BH[3], BM[3], BL[3]); SBAR();
        CL0(Aa, BH[4], BM[4], BL[4]);
      }
    } else {
      bf16x8 Ma0, Ma1, Ma2, Ma3, Ma4, Ma5, Mb0, Mb1, Mb2, Mb3, Mb4, Mb5;
      bf16x8 L0, L1, L2, L3, L4, L5;
      bf16x8 BH[5], BM[5];
      if (tg == 0) {   // taps 0..3, products Am*(Bh,Bm) + Al*Bh
        RDA6(Ma, 1, 0);
#pragma unroll
        for (int k2 = 0; k2 < 4; ++k2) { BH[k2] = LW(0, k2, c); BM[k2] = LW(1, k2, c); }
        if (c < 31) stageX(c + 1, (c + 1) & 1);
        SBAR();
        RDA6(L, 2, 0); RDA6(Mb, 1, 1); SBAR();
        CL1A(Ma, BH[0], BM[0]); CL1B(L, BH[0]); SBAR();
        RDA6(L, 2, 1); RDA6(Ma, 1, 2); SBAR();
        CL1A(Mb, BH[1], BM[1]); CL1B(L, BH[1]); SBAR();
        RDA6(L, 2, 2); RDA6(Mb, 1, 3); SBAR();
        CL1A(Ma, BH[2], BM[2]); CL1B(L, BH[2]); SBAR();
        RDA6(L, 2, 3); SBAR();
        CL1A(Mb, BH[3], BM[3]); CL1B(L, BH[3]);
      } else {         // taps 4..8
        RDA6(Ma, 1, 4);
#pragma unroll
        for (int k2 = 0; k2 < 5; ++k2) { BH[k2] = LW(0, 4 + k2, c); BM[k2] = LW(1, 4 + k2, c); }
        if (c < 31) stageX(c + 1, (c + 1) & 1);
        SBAR();
        RDA6(L, 2, 4); RDA6(Mb, 1, 5); SBAR();
        CL1A(Ma, BH[0], BM[0]); CL1B(L, BH[0]); SBAR();
        RDA6(L, 2, 5); RDA6(Ma, 1, 6); SBAR();
        CL1A(Mb, BH[1], BM[1]); CL1B(L, BH[1]); SBAR();
        RDA6(L, 2, 6); RDA6(Mb, 1, 7); SBAR();
        CL1A(Ma, BH[2], BM[2]); CL1B(L, BH[2]); SBAR();
        RDA6(L, 2, 7); RDA6(Ma, 1, 8); SBAR();
        CL1A(Mb, BH[3], BM[3]); CL1B(L, BH[3]); SBAR();
        RDA6(L, 2, 8); SBAR();
        CL1A(Ma, BH[4], BM[4]); CL1B(L, BH[4]);
      }
    }
    __syncthreads();
  }

  // epilogue: two mt-halves; 4 partials in Lf[4][96][36]; combine+bias+leaky+split
  float* Lf = (float*)smem;
#pragma unroll
  for (int half = 0; half < 2; ++half) {
    if (half == 0) { STO(acc0, 0); STO(acc1, 1); STO(acc2, 2); }
    else           { STO(acc3, 0); STO(acc4, 1); STO(acc5, 2); }
    __syncthreads();
    for (int u = tid; u < 1152; u += 256) {
      int pl = u / 384, rem = u - pl*384;
      int gq = rem / 96, lp = rem - gq*96;
      int lpos = half*96 + lp;
      if (lpos < CNT) {
        int p = PB + lpos;
        int pp = p + 2*(p/19) + 22;
        const float* bb = bias + slice*32 + gq*8;
        bf16x8 o;
#pragma unroll
        for (int j = 0; j < 8; ++j) {
          int coix = lp*36 + gq*8 + j;
          float v = Lf[coix] + Lf[3456 + coix] + Lf[6912 + coix] + Lf[10368 + coix] + bb[j];
          v = v > 0.f ? v : 0.1f*v;
          __bf16 hh = (__bf16)v; float r1 = v - (float)hh;
          __bf16 mm = (__bf16)r1;
          o[j] = pl == 0 ? hh : (pl == 1 ? mm : (__bf16)(r1 - (float)mm));
        }
        *(bf16x8*)(Xd + (((size_t)pl*16 + b)*64 + slice*4 + gq)*GSTR + (size_t)pp*8) = o;
      }
    }
    __syncthreads();
  }

  // zero output halo rows for this h-half (consumers need zero padding)
  // halo columns are x=0 and x=20 of each padded row (x=19 is VALID output!)
  const int nh = h ? 39 : 41;
  for (int u = tid; u < 12*nh; u += 256) {
    int pl = u / (4*nh); int rem = u - pl*4*nh;
    int gq = rem / nh; int ci2 = rem - gq*nh;
    int rowpos;
    if (ci2 < 21) rowpos = h ? (420 + ci2) : ci2;
    else { int q = ci2 - 21; rowpos = ((h ? 11 : 1) + (q >> 1))*21 + 20*(q & 1); }
    bf16x8 z = {};
    *(bf16x8*)(Xd + (((size_t)pl*16 + b)*64 + slice*4 + gq)*GSTR + (size_t)rowpos*8) = z;
  }
}

// ---------------- 1x1 heads on split planes ----------------
__global__ __launch_bounds__(256) void head_rf_k(
    const __bf16* __restrict__ F, const float* __restrict__ wobj,
    const float* __restrict__ bobj, const float* __restrict__ wreg,
    const float* __restrict__ breg, float* __restrict__ obj, float* __restrict__ regp)
{
  int gw = blockIdx.x*4 + (threadIdx.x >> 6);
  if (gw >= NB*NPOS) return;
  int lane = threadIdx.x & 63;
  int b = gw / NPOS, p = gw % NPOS;
  int pp = p + 2*(p/19) + 22;
  const __bf16* base = F + (((size_t)b)*64 + lane)*GSTR + (size_t)pp*8;
  bf16x8 v0 = *(const bf16x8*)base;
  bf16x8 v1 = *(const bf16x8*)(base + PLANE);
  bf16x8 v2 = *(const bf16x8*)(base + 2*PLANE);
  float f[8];
#pragma unroll
  for (int j = 0; j < 8; ++j) f[j] = (float)v0[j] + (float)v1[j] + (float)v2[j];
#pragma unroll
  for (int o = 0; o < 5; ++o) {
    const float* wp = (o == 0) ? wobj : wreg + (o-1)*CCH;
    float4 wa = *(const float4*)(wp + lane*8);
    float4 wb = *(const float4*)(wp + lane*8 + 4);
    float s2 = f[0]*wa.x + f[1]*wa.y + f[2]*wa.z + f[3]*wa.w
             + f[4]*wb.x + f[5]*wb.y + f[6]*wb.z + f[7]*wb.w;
#pragma unroll
    for (int d = 32; d; d >>= 1) s2 += __shfl_xor(s2, d);
    if (lane == 0) {
      if (o == 0) obj[gw] = s2 + bobj[0];
      else regp[(size_t)gw*4 + (o-1)] = s2 + breg[o-1];
    }
  }
}

__global__ __launch_bounds__(256) void head_cls_k(
    const __bf16* __restrict__ F, const float* __restrict__ wcls,
    const float* __restrict__ bcls, float* __restrict__ clsp)
{
  int gw = blockIdx.x*4 + (threadIdx.x >> 6);
  if (gw >= NB*NPOS) return;
  int lane = threadIdx.x & 63;
  int b = gw / NPOS, p = gw % NPOS;
  int pp = p + 2*(p/19) + 22;
  const __bf16* base = F + (((size_t)b)*64 + lane)*GSTR + (size_t)pp*8;
  bf16x8 v0 = *(const bf16x8*)base;
  bf16x8 v1 = *(const bf16x8*)(base + PLANE);
  bf16x8 v2 = *(const bf16x8*)(base + 2*PLANE);
  float f[8];
#pragma unroll
  for (int j = 0; j < 8; ++j) f[j] = (float)v0[j] + (float)v1[j] + (float)v2[j];
#pragma unroll
  for (int o = 0; o < NCLS; ++o) {
    const float* wp = wcls + o*CCH;
    float4 wa = *(const float4*)(wp + lane*8);
    float4 wb = *(const float4*)(wp + lane*8 + 4);
    float s2 = f[0]*wa.x + f[1]*wa.y + f[2]*wa.z + f[3]*wa.w
             + f[4]*wb.x + f[5]*wb.y + f[6]*wb.z + f[7]*wb.w;
#pragma unroll
    for (int d = 32; d; d >>= 1) s2 += __shfl_xor(s2, d);
    if (lane == 0) clsp[(size_t)gw*NCLS + o] = s2 + bcls[o];
  }
}

// ---------------- decode boxes + scores + argmax -------------------------
__global__ void decode_k(const float* __restrict__ obj, const float* __restrict__ clsp,
                         const float* __restrict__ regp, float* __restrict__ outb)
{
  int i = blockIdx.x * 256 + threadIdx.x;
  if (i >= NB * NPOS) return;
  int p = i % NPOS;
  float gx = (float)(p % FMPX), gy = (float)(p / FMPX);
  float4 rg = *(const float4*)&regp[(size_t)i * 4];
  float cx = 1.f / (1.f + expf(-rg.x)) + gx;
  float cy = 1.f / (1.f + expf(-rg.y)) + gy;
  float whw = expf(rg.z), whh = expf(rg.w);
  float x1 = fminf(fmaxf((cx - whw * 0.5f) * BSCALE, 0.f), 1.f);
  float y1 = fminf(fmaxf((cy - whh * 0.5f) * BSCALE, 0.f), 1.f);
  float x2 = fminf(fmaxf((cx + whw * 0.5f) * BSCALE, 0.f), 1.f);
  float y2 = fminf(fmaxf((cy + whh * 0.5f) * BSCALE, 0.f), 1.f);
  outb[(size_t)i * 4 + 0] = x1; outb[(size_t)i * 4 + 1] = y1;
  outb[(size_t)i * 4 + 2] = x2; outb[(size_t)i * 4 + 3] = y2;

  float so = 1.f / (1.f + expf(-obj[i]));
  float cv[20];
  const float4* cp = (const float4*)&clsp[(size_t)i * 20];
#pragma unroll
  for (int q = 0; q < 5; q++) {
    float4 v4 = cp[q];
    cv[q * 4] = v4.x; cv[q * 4 + 1] = v4.y; cv[q * 4 + 2] = v4.z; cv[q * 4 + 3] = v4.w;
  }
  float mx = cv[0];
#pragma unroll
  for (int c = 1; c < 20; c++) mx = fmaxf(mx, cv[c]);
  float sum = 0.f;
#pragma unroll
  for (int c = 0; c < 20; c++) { cv[c] = expf(cv[c] - mx); sum += cv[c]; }
  float inv = so / sum;
  float best = -1.f; int bi = 0;
#pragma unroll
  for (int c = 0; c < 20; c++) { float s = cv[c] * inv; if (s > best) { best = s; bi = c; } }
  outb[SC_OFF + i] = best;
  outb[CLS_OFF + i] = (float)bi;
  outb[KEEP_OFF + i] = 0.f;
}

// ---------------- per (batch,class) greedy NMS ----------------------------
__device__ inline unsigned ordf(float f) {
  unsigned u = __float_as_uint(f);
  return (u & 0x80000000u) ? ~u : (u | 0x80000000u);
}

__global__ __launch_bounds__(64) void nms_k(const float* __restrict__ outb, float* __restrict__ keep_out)
{
  int b = blockIdx.x / NCLS, c = blockIdx.x % NCLS;
  int lane = threadIdx.x;
  __shared__ unsigned long long keys[512];
  __shared__ float bx1[384], by1[384], bx2[384], by2[384], bar[384];
  __shared__ unsigned kp[384];
  __shared__ int sj[384];

  for (int i = lane; i < 512; i += 64) {
    unsigned long long key = 0ULL;
    if (i < NPOS) {
      float sc = outb[SC_OFF + b * NPOS + i];
      int ci = (int)outb[CLS_OFF + b * NPOS + i];
      float s = (ci == c && sc >= CONF_T) ? sc : -1.0f;
      key = ((unsigned long long)ordf(s) << 32) | (unsigned)(~(unsigned)i);
    }
    keys[i] = key;
  }
  __syncthreads();
  for (int kk = 2; kk <= 512; kk <<= 1) {
    for (int jj = kk >> 1; jj > 0; jj >>= 1) {
      for (int i = lane; i < 512; i += 64) {
        int l2 = i ^ jj;
        if (l2 > i) {
          unsigned long long a = keys[i], bb2 = keys[l2];
          bool dir = (i & kk) == 0;
          bool sw = dir ? (a < bb2) : (a > bb2);
          if (sw) { keys[i] = bb2; keys[l2] = a; }
        }
      }
      __syncthreads();
    }
  }
  unsigned ordc = ordf(CONF_T);
  int nvalid = 0;
  for (int i = lane; i < 384; i += 64) {
    unsigned long long key = keys[i];
    unsigned hi = (unsigned)(key >> 32);
    int j = (int)(~(unsigned)key);
    bool valid = (key != 0ULL) && (hi >= ordc);
    kp[i] = valid ? 1u : 0u;
    if (valid) {
      const float* bp = &outb[(size_t)(b * NPOS + j) * 4];
      float x1 = bp[0], y1 = bp[1], x2 = bp[2], y2 = bp[3];
      bx1[i] = x1; by1[i] = y1; bx2[i] = x2; by2[i] = y2;
      bar[i] = (x2 - x1) * (y2 - y1);
      sj[i] = j;
    } else { bx1[i] = 0; by1[i] = 0; bx2[i] = 0; by2[i] = 0; bar[i] = 0; sj[i] = 0; }
    nvalid += __popcll(__ballot(valid));
  }
  __syncthreads();
  for (int i = 0; i < nvalid; ++i) {
    if (kp[i]) {
      float x1i = bx1[i], y1i = by1[i], x2i = bx2[i], y2i = by2[i], ai = bar[i];
      for (int j2 = i + 1 + lane; j2 < nvalid; j2 += 64) {
        if (kp[j2]) {
          float ww = fmaxf(1e-28f, fminf(x2i, bx2[j2]) - fmaxf(x1i, bx1[j2]));
          float hh = fmaxf(1e-28f, fminf(y2i, by2[j2]) - fmaxf(y1i, by1[j2]));
          float inter = ww * hh;
          float iou = inter / (ai + bar[j2] - inter + 1e-14f);
          if (iou > NMS_TH) kp[j2] = 0u;
        }
      }
    }
    __syncthreads();
  }
  for (int i = lane; i < 384; i += 64)
    if (kp[i]) keep_out[b * NPOS + sj[i]] = 1.0f;
}

extern "C" void kernel_launch(void* const* d_in, const int* in_sizes, int n_in,
                              void* d_out, int out_size, void* d_ws, size_t ws_size,
                              hipStream_t stream)
{
  const float* x      = (const float*)d_in[0];
  const float* w_cls1 = (const float*)d_in[1];  const float* b_cls1 = (const float*)d_in[2];
  const float* w_cls2 = (const float*)d_in[3];  const float* b_cls2 = (const float*)d_in[4];
  const float* w_reg1 = (const float*)d_in[5];  const float* b_reg1 = (const float*)d_in[6];
  const float* w_reg2 = (const float*)d_in[7];  const float* b_reg2 = (const float*)d_in[8];
  const float* w_reg3 = (const float*)d_in[9];  const float* b_reg3 = (const float*)d_in[10];
  const float* w_reg4 = (const float*)d_in[11]; const float* b_reg4 = (const float*)d_in[12];
  const float* w_obj  = (const float*)d_in[13]; const float* b_obj  = (const float*)d_in[14];
  const float* w_clsh = (const float*)d_in[15]; const float* b_clsh = (const float*)d_in[16];
  const float* w_regh = (const float*)d_in[17]; const float* b_regh = (const float*)d_in[18];
  float* outb = (float*)d_out;

  __bf16* XsA = (__bf16*)d_ws;
  __bf16* XsB = XsA + 3*PLANE;
  __bf16* Wg  = XsB + 3*PLANE;
  float* obj  = (float*)(Wg + (size_t)7077888);
  float* regp = obj + NB*NPOS;
  float* clsp = regp + (size_t)NB*NPOS*4;

  auto conv = [&](const float* wsrc, const float* bsrc, const __bf16* src, __bf16* dst) {
    repack_k<<<dim3(16, 32), 256, 0, stream>>>(wsrc, Wg);
    conv3x3_mfma<<<512, 256, 0, stream>>>(src, Wg, bsrc, dst);
  };

  split_x_k<<<dim3(64, NB), 256, 0, stream>>>(x, XsA);
  conv(w_reg1, b_reg1, XsA, XsB);
  conv(w_reg2, b_reg2, XsB, XsA);
  conv(w_reg3, b_reg3, XsA, XsB);
  conv(w_reg4, b_reg4, XsB, XsA);                    // rf = XsA
  head_rf_k<<<1444, 256, 0, stream>>>(XsA, w_obj, b_obj, w_regh, b_regh, obj, regp);
  split_x_k<<<dim3(64, NB), 256, 0, stream>>>(x, XsB);
  conv(w_cls1, b_cls1, XsB, XsA);
  conv(w_cls2, b_cls2, XsA, XsB);                    // cf = XsB
  head_cls_k<<<1444, 256, 0, stream>>>(XsB, w_clsh, b_clsh, clsp);
  decode_k<<<(NB * NPOS + 255) / 256, 256, 0, stream>>>(obj, clsp, regp, outb);
  nms_k<<<NB * NCLS, 64, 0, stream>>>(outb, outb + KEEP_OFF);
}